// Round 10
// baseline (490.542 us; speedup 1.0000x reference)
//
#include <hip/hip_runtime.h>
#include <hip/hip_bf16.h>

typedef _Float16 h16;
typedef __attribute__((ext_vector_type(8))) _Float16 halfx8;
typedef __attribute__((ext_vector_type(4))) _Float16 halfx4;
typedef __attribute__((ext_vector_type(4))) float f32x4;

__device__ __forceinline__ void gload_lds16(const void* g, void* l) {
  __builtin_amdgcn_global_load_lds((const __attribute__((address_space(1))) unsigned int*)g,
                                   (__attribute__((address_space(3))) unsigned int*)l, 16, 0, 0);
}
__device__ __forceinline__ unsigned umax_(unsigned a, unsigned b) { return a > b ? a : b; }
__device__ __forceinline__ unsigned umin_(unsigned a, unsigned b) { return a < b ? a : b; }

// tanh-form GELU via sigmoid: x*sigmoid(1.5957691x + 0.0713548x^3)
__device__ __forceinline__ float fast_gelu(float v) {
  float x2 = v * v;
  float w_ = v * fmaf(x2, 0.0713548163f, 1.5957691216f);
  float e = __expf(w_);
  float r = 1.f / (1.f + e);
  return v * e * r;
}

// ---------------- merged prep: text_kv (blocks 0-159) + conv_all (160-2719) + ln1 (2720+) ----
__global__ __launch_bounds__(256) void prep_kernel(
    const float* __restrict__ tf, const float* __restrict__ kw, const float* __restrict__ kb,
    const float* __restrict__ vw, const float* __restrict__ vb, const float* __restrict__ lsp,
    h16* __restrict__ ko, h16* __restrict__ vo, float* __restrict__ padf,
    const float* __restrict__ qw, const float* __restrict__ ow,
    const float* __restrict__ f1w, const float* __restrict__ f2w,
    h16* __restrict__ qwT, h16* __restrict__ owT,
    h16* __restrict__ f1T, h16* __restrict__ f2T,
    const float* __restrict__ vis, const float* __restrict__ n1w, const float* __restrict__ n1b,
    const float* __restrict__ gw, const float* __restrict__ gb,
    h16* __restrict__ x, float* __restrict__ gate)
{
  __shared__ h16 st[4 * 512];
  __shared__ float kro[4 * 256];
  __shared__ float ssc[4];
  int bid = blockIdx.x, tid = threadIdx.x;
  int lane = tid & 63, wid = tid >> 6;

  if (bid < 160) {
    // ---------------- text_kv body ----------------
    int b = bid / 20, tg = bid % 20, t0 = tg * 4;
    for (int i = tid; i < 4 * 512; i += 256) {
      int tl = i >> 9, j = i & 511, t = t0 + tl;
      float v = (t < 77) ? tf[((size_t)b * 77 + t) * 512 + j] : 0.f;
      st[i] = (h16)v;
    }
    __syncthreads();
    {
      int t = t0 + wid;
      float a = 0.f;
      #pragma unroll
      for (int j = 0; j < 8; j++) a += fabsf((float)st[wid * 512 + lane + j * 64]);
      #pragma unroll
      for (int o = 32; o; o >>= 1) a += __shfl_xor(a, o);
      if (lane == 0) padf[b * 80 + t] = (a <= 1e-6f) ? -1e30f : 0.f;
    }
    int c = tid;
    float kacc[4], vacc[4];
    #pragma unroll
    for (int tl = 0; tl < 4; tl++) { kacc[tl] = kb[c]; vacc[tl] = vb[c]; }
    for (int j = 0; j < 512; j++) {
      float wkv = kw[(size_t)j * 256 + c];
      float wvv = vw[(size_t)j * 256 + c];
      #pragma unroll
      for (int tl = 0; tl < 4; tl++) {
        float xv = (float)st[tl * 512 + j];
        kacc[tl] += xv * wkv; vacc[tl] += xv * wvv;
      }
    }
    #pragma unroll
    for (int tl = 0; tl < 4; tl++) kro[tl * 256 + c] = kacc[tl] * kacc[tl];
    __syncthreads();
    {
      float s2 = kro[wid * 256 + lane] + kro[wid * 256 + lane + 64]
               + kro[wid * 256 + lane + 128] + kro[wid * 256 + lane + 192];
      #pragma unroll
      for (int o = 32; o; o >>= 1) s2 += __shfl_xor(s2, o);
      if (lane == 0) {
        float ls = lsp[0];
        float scale = __expf(fminf(fmaxf(ls, -2.f), 2.f)) * rsqrtf(32.f);
        ssc[wid] = scale / fmaxf(sqrtf(s2), 1e-6f);
      }
    }
    __syncthreads();
    int h = c >> 5, d = c & 31, g = d >> 3, e = d & 7;
    #pragma unroll
    for (int tl = 0; tl < 4; tl++) {
      int t = t0 + tl;
      int kt = t >> 4, l15 = t & 15, ln = g * 16 + l15;
      size_t koff = ((((size_t)(b * 8 + h) * 5 + kt) * 64) + ln) * 8 + e;
      size_t voff = (((size_t)(b * 8 + h) * 80) + t) * 32 + d;
      ko[koff] = (t < 77) ? (h16)(kacc[tl] * ssc[tl]) : (h16)0.f;
      vo[voff] = (t < 77) ? (h16)vacc[tl] : (h16)0.f;
    }
  } else if (bid < 2720) {
    // ---------------- conv_all body ----------------
    int cb = bid - 160;
    const float* in; h16* out; int logN, K, base;
    if (cb < 256)       { in = qw;  out = qwT; logN = 8;  K = 256;  base = 0; }
    else if (cb < 512)  { in = ow;  out = owT; logN = 8;  K = 256;  base = 256; }
    else if (cb < 1536) { in = f1w; out = f1T; logN = 10; K = 256;  base = 512; }
    else                { in = f2w; out = f2T; logN = 8;  K = 1024; base = 1536; }
    int idx = (cb - base) * 256 + tid;
    int k = idx >> logN, n = idx & ((1 << logN) - 1);
    out[(size_t)n * K + k] = (h16)in[idx];
  } else {
    // ---------------- ln1 body ----------------
    size_t row = (size_t)(bid - 2720) * 4 + wid;
    const float4 v = ((const float4*)(vis + row * 256))[lane];
    float s = v.x + v.y + v.z + v.w;
    float q = v.x * v.x + v.y * v.y + v.z * v.z + v.w * v.w;
    #pragma unroll
    for (int o = 32; o; o >>= 1) { s += __shfl_xor(s, o); q += __shfl_xor(q, o); }
    float mean = s * (1.f / 256.f);
    float rstd = rsqrtf(q * (1.f / 256.f) - mean * mean + 1e-5f);
    float4 wv = ((const float4*)n1w)[lane], bv = ((const float4*)n1b)[lane];
    float x0 = (v.x - mean) * rstd * wv.x + bv.x;
    float x1 = (v.y - mean) * rstd * wv.y + bv.y;
    float x2 = (v.z - mean) * rstd * wv.z + bv.z;
    float x3 = (v.w - mean) * rstd * wv.w + bv.w;
    float4 gv = ((const float4*)gw)[lane];
    float g = x0 * gv.x + x1 * gv.y + x2 * gv.z + x3 * gv.w;
    #pragma unroll
    for (int o = 32; o; o >>= 1) g += __shfl_xor(g, o);
    if (lane == 0) gate[row] = 1.f / (1.f + __expf(-(g + gb[0])));
    halfx4 o4; o4[0] = (h16)x0; o4[1] = (h16)x1; o4[2] = (h16)x2; o4[3] = (h16)x3;
    ((halfx4*)(x + row * 256))[lane] = o4;
  }
}

// ---------------- fused gemmQ + attention + gemmO/LN2 v2 ----------------
// R6's QAO with the diagnosed flaw fixed: gemmO keeps PER-WAVE 64-col B slices (no 4x
// B-read amplification). attn o8s (registers) is routed to the other waves via an 8KB
// LDS A-slice per k0 (2 ds_write_b128/thread) — gemmO phase is otherwise bit-identical
// to the standalone gemmO. Saves qh entirely (128 MB HBM) + one launch + A-DMA.
__global__ __launch_bounds__(256) void gemmQAO_kernel(const h16* __restrict__ A,
    const h16* __restrict__ Wt, const float* __restrict__ bias,
    const h16* __restrict__ kk,   // kT[b][h][kt][lane][8]
    const h16* __restrict__ vv,   // vT[b][h][80][32]
    const float* __restrict__ padf,
    const h16* __restrict__ Ot,   // owT [n][k] h16
    const float* __restrict__ ob,
    const h16* __restrict__ x, const float* __restrict__ gate,
    const float* __restrict__ alphap, const float* __restrict__ w2,
    const float* __restrict__ b2, h16* __restrict__ outp)   // y2
{
  __shared__ char sA[8192];
  __shared__ char sB[32768];
  int m0 = blockIdx.x * 64;
  int tid = threadIdx.x, lane = tid & 63, wid = tid >> 6;
  int wn = wid;
  int l15 = lane & 15, l4 = lane >> 4, xk = l15 & 7;
  f32x4 acc[4][4];
  #pragma unroll
  for (int a = 0; a < 4; a++)
    #pragma unroll
    for (int b2_ = 0; b2_ < 4; b2_++) acc[a][b2_] = (f32x4){0.f, 0.f, 0.f, 0.f};
  const size_t sa = 512;
  int srow = lane >> 3;
  int scol = ((lane & 7) ^ srow) * 16;
  const char* Ab = (const char*)A + (size_t)m0 * sa + scol;
  const char* Bb = (const char*)Wt + scol;
  for (int k0 = 0; k0 < 256; k0 += 64) {
    #pragma unroll
    for (int cc = 0; cc < 2; cc++) {
      int ch = wid * 2 + cc;
      gload_lds16(Ab + (size_t)(ch * 8 + srow) * sa + k0 * 2, sA + ch * 1024);
    }
    #pragma unroll
    for (int cc = 0; cc < 8; cc++) {
      int ch = wid * 8 + cc;
      gload_lds16(Bb + (size_t)(ch * 8 + srow) * sa + k0 * 2, sB + ch * 1024);
    }
    asm volatile("s_waitcnt vmcnt(0)" ::: "memory");
    __syncthreads();
    #pragma unroll
    for (int ks = 0; ks < 2; ks++) {
      halfx8 af[4], bf[4];
      #pragma unroll
      for (int f = 0; f < 4; f++) {
        af[f] = *(const halfx8*)(sA + (f * 16 + l15) * 128 + (((ks * 4 + l4) ^ xk) * 16));
        bf[f] = *(const halfx8*)(sB + (wn * 64 + f * 16 + l15) * 128 + (((ks * 4 + l4) ^ xk) * 16));
      }
      #pragma unroll
      for (int fm = 0; fm < 4; fm++)
        #pragma unroll
        for (int fn = 0; fn < 4; fn++)
          acc[fm][fn] = __builtin_amdgcn_mfma_f32_16x16x32_f16(af[fm], bf[fn], acc[fm][fn], 0, 0, 0);
    }
    __syncthreads();
  }
  float bv[4];
  #pragma unroll
  for (int fn = 0; fn < 4; fn++) bv[fn] = bias[wn * 64 + fn * 16 + l15];
  float ps[4][4];
  #pragma unroll
  for (int fm = 0; fm < 4; fm++)
    #pragma unroll
    for (int r = 0; r < 4; r++) {
      float s = 0.f;
      #pragma unroll
      for (int fn = 0; fn < 4; fn++) {
        float v = acc[fm][fn][r] + bv[fn];
        acc[fm][fn][r] = v;
        s += v * v;
      }
      ps[fm][r] = s;
    }
  #pragma unroll
  for (int o = 1; o <= 8; o <<= 1)
    #pragma unroll
    for (int fm = 0; fm < 4; fm++)
      #pragma unroll
      for (int r = 0; r < 4; r++) ps[fm][r] += __shfl_xor(ps[fm][r], o);
  if (l15 == 0) {
    #pragma unroll
    for (int fm = 0; fm < 4; fm++)
      #pragma unroll
      for (int r = 0; r < 4; r++)
        ((float*)sA)[(fm * 16 + l4 * 4 + r) * 4 + wn] = ps[fm][r];
  }
  __syncthreads();
  // normalized q -> sB as [64 rows][256 cols] h16, granule ^ (row&7) swizzle
  #pragma unroll
  for (int fm = 0; fm < 4; fm++)
    #pragma unroll
    for (int r = 0; r < 4; r++) {
      const float* p = (const float*)sA + (fm * 16 + l4 * 4 + r) * 4;
      float S = p[0] + p[1] + p[2] + p[3];
      float sc = 1.f / fmaxf(sqrtf(S), 1e-6f);
      int row = fm * 16 + l4 * 4 + r;
      #pragma unroll
      for (int fn = 0; fn < 4; fn++) {
        int col = wn * 64 + fn * 16 + l15;
        ((h16*)(sB + row * 512 + (((col >> 3) ^ (row & 7)) * 16)))[col & 7] =
            (h16)(acc[fm][fn][r] * sc);
      }
    }
  __syncthreads();

  // ---- attn phase: wave = rows wid*16..+16; qf frags from LDS; o8s kept in regs ----
  halfx8 o8s[8];
  {
    int b = blockIdx.x >> 8;
    int base4 = l4 * 4;
    float pad4[5][4];
    #pragma unroll
    for (int kt = 0; kt < 5; kt++) {
      float4 p4 = *(const float4*)&padf[b * 80 + kt * 16 + base4];
      pad4[kt][0] = p4.x; pad4[kt][1] = p4.y; pad4[kt][2] = p4.z; pad4[kt][3] = p4.w;
    }
    const char* qsrc = sB + (wid * 16 + l15) * 512;
    int rk = l15 & 7;
    #pragma unroll
    for (int h = 0; h < 8; h++) {
      halfx8 qf = *(const halfx8*)(qsrc + (((h * 4 + l4) ^ rk) * 16));
      const h16* kph = kk + (((size_t)(b * 8 + h) * 5) * 64 + lane) * 8;
      const h16* vph = vv + ((size_t)(b * 8 + h) * 80) * 32 + l4 * 8;
      f32x4 acc5[5];
      #pragma unroll
      for (int kt = 0; kt < 5; kt++) {
        halfx8 kf = *(const halfx8*)(kph + kt * 512);
        acc5[kt] = __builtin_amdgcn_mfma_f32_16x16x32_f16(kf, qf, (f32x4){0.f, 0.f, 0.f, 0.f}, 0, 0, 0);
      }
      unsigned pv0 = 0u, pv1 = 0u, pv2 = 0u, pv3 = 0u, pv4 = 0u;
      #pragma unroll
      for (int kt = 0; kt < 5; kt++) {
        #pragma unroll
        for (int r = 0; r < 4; r++) {
          float s = acc5[kt][r] + pad4[kt][r];
          int bi = __float_as_int(s);
          unsigned u = ((unsigned)(bi ^ ((bi >> 31) | (int)0x80000000)) & 0xFFFFFF80u)
                     | (unsigned)(base4 + kt * 16 + r);
          unsigned a;
          a = umax_(pv0, u); u = umin_(pv0, u); pv0 = a;
          a = umax_(pv1, u); u = umin_(pv1, u); pv1 = a;
          a = umax_(pv2, u); u = umin_(pv2, u); pv2 = a;
          a = umax_(pv3, u); u = umin_(pv3, u); pv3 = a;
          pv4 = umax_(pv4, u);
        }
      }
      #pragma unroll
      for (int mrd = 0; mrd < 2; mrd++) {
        int msk = mrd ? 32 : 16;
        unsigned b0 = (unsigned)__shfl_xor((int)pv0, msk);
        unsigned b1 = (unsigned)__shfl_xor((int)pv1, msk);
        unsigned b2_ = (unsigned)__shfl_xor((int)pv2, msk);
        unsigned b3 = (unsigned)__shfl_xor((int)pv3, msk);
        unsigned b4 = (unsigned)__shfl_xor((int)pv4, msk);
        unsigned c0 = umax_(pv0, b0);
        unsigned c1 = umax_(umax_(umin_(pv0, b0), pv1), b1);
        unsigned c2 = umax_(umax_(umin_(pv0, b1), umin_(pv1, b0)), umax_(pv2, b2_));
        unsigned c3 = umax_(umax_(umax_(umin_(pv0, b2_), umin_(pv1, b1)), umin_(pv2, b0)), umax_(pv3, b3));
        unsigned c4 = umax_(umax_(umax_(umin_(pv0, b3), umin_(pv1, b2_)),
                                  umax_(umin_(pv2, b1), umin_(pv3, b0))), umax_(pv4, b4));
        pv0 = c0; pv1 = c1; pv2 = c2; pv3 = c3; pv4 = c4;
      }
      unsigned pvs[5] = {pv0, pv1, pv2, pv3, pv4};
      float pw[5]; int ti[5]; float den = 0.f;
      #pragma unroll
      for (int k = 0; k < 5; k++) {
        unsigned u = pvs[k];
        int sg = ((int)u) >> 31;
        float tv = __int_as_float(u ^ (0x80000000u | (unsigned)~sg));
        ti[k] = (int)(u & 0x7Fu);
        pw[k] = __expf(tv);
        den += pw[k];
      }
      float inv = 1.f / den;
      halfx8 o8 = {};
      #pragma unroll
      for (int k = 0; k < 5; k++) {
        h16 ph = (h16)(pw[k] * inv);
        halfx8 v = *(const halfx8*)(vph + ti[k] * 32);
        halfx8 p8 = {ph, ph, ph, ph, ph, ph, ph, ph};
        o8 = o8 + p8 * v;
      }
      o8s[h] = o8;
    }
  }

  // all q reads complete; sA/sB free for the gemmO phase
  asm volatile("" ::: "memory");
  __builtin_amdgcn_s_barrier();
  asm volatile("" ::: "memory");

  // ---- gemmO phase (per-wave 64-col B slices, A-slice via 8KB LDS per k0) ----
  f32x4 acc2[4][4];
  #pragma unroll
  for (int a = 0; a < 4; a++)
    #pragma unroll
    for (int b_ = 0; b_ < 4; b_++) acc2[a][b_] = (f32x4){0.f, 0.f, 0.f, 0.f};
  const char* Ob = (const char*)Ot + scol;
  {
    int arow = wid * 16 + l15;            // this thread's A row
    int ark = arow & 7;                   // swizzle key for writes
    for (int k0 = 0; k0 < 256; k0 += 64) {
      // A-slice [64 rows][64 k] <- o8s (each thread: 2 ds_write_b128)
      #pragma unroll
      for (int ks = 0; ks < 2; ks++)
        *(halfx8*)(sA + arow * 128 + (((ks * 4 + l4) ^ ark) * 16)) = o8s[(k0 >> 5) + ks];
      // B tile (owT) via DMA (same as standalone gemmO)
      #pragma unroll
      for (int cc = 0; cc < 8; cc++) {
        int ch = wid * 8 + cc;
        gload_lds16(Ob + (size_t)(ch * 8 + srow) * sa + k0 * 2, sB + ch * 1024);
      }
      asm volatile("s_waitcnt vmcnt(0)" ::: "memory");
      asm volatile("s_waitcnt lgkmcnt(0)" ::: "memory");
      __syncthreads();
      #pragma unroll
      for (int ks = 0; ks < 2; ks++) {
        halfx8 af[4], bf[4];
        #pragma unroll
        for (int f = 0; f < 4; f++) {
          af[f] = *(const halfx8*)(sA + (f * 16 + l15) * 128 + (((ks * 4 + l4) ^ xk) * 16));
          bf[f] = *(const halfx8*)(sB + (wn * 64 + f * 16 + l15) * 128 + (((ks * 4 + l4) ^ xk) * 16));
        }
        #pragma unroll
        for (int fm = 0; fm < 4; fm++)
          #pragma unroll
          for (int fn = 0; fn < 4; fn++)
            acc2[fm][fn] = __builtin_amdgcn_mfma_f32_16x16x32_f16(af[fm], bf[fn], acc2[fm][fn], 0, 0, 0);
      }
      __syncthreads();
    }
  }

  // ---- LN2 epilogue (identical to standalone gemmO) ----
  float bv2[4], w2v[4], b2v[4];
  #pragma unroll
  for (int fn = 0; fn < 4; fn++) {
    int col = wn * 64 + fn * 16 + l15;
    bv2[fn] = ob[col]; w2v[fn] = w2[col]; b2v[fn] = b2[col];
  }
  float al = alphap[0];
  float s1[4][4], s2[4][4];
  #pragma unroll
  for (int fm = 0; fm < 4; fm++)
    #pragma unroll
    for (int r = 0; r < 4; r++) {
      size_t row = (size_t)(m0 + fm * 16 + l4 * 4 + r);
      float ga = al * gate[row];
      float a1 = 0.f, a2 = 0.f;
      #pragma unroll
      for (int fn = 0; fn < 4; fn++) {
        float v = acc2[fm][fn][r] + bv2[fn];
        float xv = (float)x[row * 256 + wn * 64 + fn * 16 + l15];
        float y = xv + ga * v;
        acc2[fm][fn][r] = y;
        a1 += y; a2 += y * y;
      }
      s1[fm][r] = a1; s2[fm][r] = a2;
    }
  #pragma unroll
  for (int o = 1; o <= 8; o <<= 1)
    #pragma unroll
    for (int fm = 0; fm < 4; fm++)
      #pragma unroll
      for (int r = 0; r < 4; r++) {
        s1[fm][r] += __shfl_xor(s1[fm][r], o);
        s2[fm][r] += __shfl_xor(s2[fm][r], o);
      }
  if (l15 == 0) {
    #pragma unroll
    for (int fm = 0; fm < 4; fm++)
      #pragma unroll
      for (int r = 0; r < 4; r++) {
        int rr = fm * 16 + l4 * 4 + r;
        ((float*)sA)[rr * 8 + wn * 2 + 0] = s1[fm][r];
        ((float*)sA)[rr * 8 + wn * 2 + 1] = s2[fm][r];
      }
  }
  __syncthreads();
  #pragma unroll
  for (int fm = 0; fm < 4; fm++)
    #pragma unroll
    for (int r = 0; r < 4; r++) {
      int rr = fm * 16 + l4 * 4 + r;
      const float* p = (const float*)sA + rr * 8;
      float S1 = p[0] + p[2] + p[4] + p[6];
      float S2 = p[1] + p[3] + p[5] + p[7];
      float mean = S1 * (1.f / 256.f);
      float var = S2 * (1.f / 256.f) - mean * mean;
      float rstd = rsqrtf(var + 1e-5f);
      size_t row = (size_t)(m0 + rr);
      #pragma unroll
      for (int fn = 0; fn < 4; fn++) {
        float y = acc2[fm][fn][r];
        outp[row * 256 + wn * 64 + fn * 16 + l15] =
            (h16)((y - mean) * rstd * w2v[fn] + b2v[fn]);
      }
    }
}

// ---------------- fused FFN v7: v4 pipeline + swapped gemm1 -> H^T regs -> b64 H stores ----
__device__ __forceinline__ void ffn_stage_w1(const h16* __restrict__ w1t,
                                             int c, char* dW1, int tid, int wid)
{
  #pragma unroll
  for (int j = 0; j < 4; j++) {
    int i = j * 512 + tid;
    int r = i >> 5, g = i & 31;
    gload_lds16(w1t + (size_t)(c * 64 + r) * 256 + ((g ^ (r & 7)) * 8),
                dW1 + (j * 512 + wid * 64) * 16);
  }
}
__device__ __forceinline__ void ffn_stage_w2(const h16* __restrict__ w2t,
                                             int c, char* dW2, int tid, int wid)
{
  #pragma unroll
  for (int j = 0; j < 4; j++) {
    int i = j * 512 + tid;
    int r = i >> 3, g = i & 7;
    gload_lds16(w2t + (size_t)r * 1024 + c * 64 + ((g ^ (r & 7)) * 8),
                dW2 + (j * 512 + wid * 64) * 16);
  }
}

__global__ __launch_bounds__(512, 2) void ffn_fused_kernel(
    const h16* __restrict__ y2g, const h16* __restrict__ w1t, const float* __restrict__ b1,
    const h16* __restrict__ w2t, const float* __restrict__ b2, float* __restrict__ outp)
{
  __shared__ char smem[163840];
  float* sE = (float*)smem;

  int m0 = blockIdx.x * 128;
  int tid = threadIdx.x, lane = tid & 63, wid = tid >> 6;
  int l15 = lane & 15, l4 = lane >> 4;
  int wm1 = wid >> 1, wn1 = wid & 1;
  int wm2 = wid >> 2, wn2 = wid & 3;

  halfx8 afy[2][8];
  #pragma unroll
  for (int fm = 0; fm < 2; fm++) {
    size_t row = (size_t)(m0 + wm1 * 32 + fm * 16 + l15);
    #pragma unroll
    for (int ks = 0; ks < 8; ks++)
      afy[fm][ks] = *(const halfx8*)&y2g[row * 256 + ks * 32 + l4 * 8];
  }

  f32x4 acc2[4][4];
  #pragma unroll
  for (int a = 0; a < 4; a++)
    #pragma unroll
    for (int b_ = 0; b_ < 4; b_++) acc2[a][b_] = (f32x4){0.f, 0.f, 0.f, 0.f};

  ffn_stage_w1(w1t, 0, smem, tid, wid);
  // b1 as float4 (index depends on l4*4+r after the operand swap)
  float4 b1v[2];
  b1v[0] = *(const float4*)&b1[wn1 * 32 + l4 * 4];
  b1v[1] = *(const float4*)&b1[wn1 * 32 + 16 + l4 * 4];
  asm volatile("s_waitcnt vmcnt(0)" ::: "memory");
  __builtin_amdgcn_s_barrier();
  asm volatile("" ::: "memory");

  for (int c = 0; c < 16; c++) {
    int buf = c & 1;
    char* sW1c = smem + buf * 32768;
    if (c < 15) ffn_stage_w1(w1t, c + 1, smem + (buf ^ 1) * 32768, tid, wid);
    ffn_stage_w2(w2t, c, smem + 65536 + buf * 32768, tid, wid);
    float4 nb0 = {0.f, 0.f, 0.f, 0.f}, nb1 = {0.f, 0.f, 0.f, 0.f};
    if (c < 15) {
      nb0 = *(const float4*)&b1[(c + 1) * 64 + wn1 * 32 + l4 * 4];
      nb1 = *(const float4*)&b1[(c + 1) * 64 + wn1 * 32 + 16 + l4 * 4];
    }

    // gemm1(c): H^T = mfma(W1frag, y2frag) — swapped operands
    f32x4 a1[2][2];
    #pragma unroll
    for (int a = 0; a < 2; a++)
      #pragma unroll
      for (int b_ = 0; b_ < 2; b_++) a1[a][b_] = (f32x4){0.f, 0.f, 0.f, 0.f};
    __builtin_amdgcn_s_setprio(1);
    #pragma unroll
    for (int ks = 0; ks < 8; ks++) {
      #pragma unroll
      for (int fc = 0; fc < 2; fc++) {
        int nrow = wn1 * 32 + fc * 16 + l15;
        halfx8 bf = *(const halfx8*)(sW1c + (size_t)nrow * 512 + (((ks * 4 + l4) ^ (nrow & 7)) * 16));
        #pragma unroll
        for (int fm = 0; fm < 2; fm++)
          a1[fm][fc] = __builtin_amdgcn_mfma_f32_16x16x32_f16(bf, afy[fm][ks], a1[fm][fc], 0, 0, 0);
      }
    }
    __builtin_amdgcn_s_setprio(0);

    // gelu(c) -> sH[buf]: packed b64 stores, slot swizzle ^((row&7)<<1)
    {
      char* sHc = smem + 131072 + buf * 16384;
      #pragma unroll
      for (int fm = 0; fm < 2; fm++) {
        int row = wm1 * 32 + fm * 16 + l15;
        int sx = (row & 7) << 1;
        #pragma unroll
        for (int fc = 0; fc < 2; fc++) {
          int slot = wn1 * 8 + fc * 4 + l4;
          float4 bb = b1v[fc];
          halfx4 hv;
          hv[0] = (h16)fast_gelu(a1[fm][fc][0] + bb.x);
          hv[1] = (h16)fast_gelu(a1[fm][fc][1] + bb.y);
          hv[2] = (h16)fast_gelu(a1[fm][fc][2] + bb.z);
          hv[3] = (h16)fast_gelu(a1[fm][fc][3] + bb.w);
          *(halfx4*)(sHc + row * 128 + ((slot ^ sx) * 8)) = hv;
        }
      }
    }

    // gemm2(c-1): ah from sH[buf^1], bw from sW2[buf^1]
    if (c > 0) {
      char* sHp = smem + 131072 + (buf ^ 1) * 16384;
      char* sW2p = smem + 65536 + (buf ^ 1) * 32768;
      __builtin_amdgcn_s_setprio(1);
      #pragma unroll
      for (int ks = 0; ks < 2; ks++) {
        halfx8 ah[4], bw[4];
        #pragma unroll
        for (int f = 0; f < 4; f++) {
          int hrow = wm2 * 64 + f * 16 + l15;
          ah[f] = *(const halfx8*)(sHp + hrow * 128 + (((ks * 8 + l4 * 2) ^ ((hrow & 7) << 1)) * 8));
          int wrow = wn2 * 64 + f * 16 + l15;
          bw[f] = *(const halfx8*)(sW2p + (size_t)wrow * 128 + (((ks * 4 + l4) ^ (wrow & 7)) * 16));
        }
        #pragma unroll
        for (int fm = 0; fm < 4; fm++)
          #pragma unroll
          for (int fn = 0; fn < 4; fn++)
            acc2[fm][fn] = __builtin_amdgcn_mfma_f32_16x16x32_f16(ah[fm], bw[fn], acc2[fm][fn], 0, 0, 0);
      }
      __builtin_amdgcn_s_setprio(0);
    }

    asm volatile("s_waitcnt lgkmcnt(0)" ::: "memory");
    asm volatile("s_waitcnt vmcnt(0)" ::: "memory");
    __builtin_amdgcn_s_barrier();
    asm volatile("" ::: "memory");
    b1v[0] = nb0; b1v[1] = nb1;
  }

  // final gemm2(15)
  {
    char* sHp = smem + 131072 + 16384;
    char* sW2p = smem + 65536 + 32768;
    __builtin_amdgcn_s_setprio(1);
    #pragma unroll
    for (int ks = 0; ks < 2; ks++) {
      halfx8 ah[4], bw[4];
      #pragma unroll
      for (int f = 0; f < 4; f++) {
        int hrow = wm2 * 64 + f * 16 + l15;
        ah[f] = *(const halfx8*)(sHp + hrow * 128 + (((ks * 8 + l4 * 2) ^ ((hrow & 7) << 1)) * 8));
        int wrow = wn2 * 64 + f * 16 + l15;
        bw[f] = *(const halfx8*)(sW2p + (size_t)wrow * 128 + (((ks * 4 + l4) ^ (wrow & 7)) * 16));
      }
      #pragma unroll
      for (int fm = 0; fm < 4; fm++)
        #pragma unroll
        for (int fn = 0; fn < 4; fn++)
          acc2[fm][fn] = __builtin_amdgcn_mfma_f32_16x16x32_f16(ah[fm], bw[fn], acc2[fm][fn], 0, 0, 0);
    }
    __builtin_amdgcn_s_setprio(0);
  }

  int rowl = tid >> 3, cg = tid & 7;
  #pragma unroll
  for (int half = 0; half < 2; half++) {
    if (wm2 == half) {
      #pragma unroll
      for (int fm = 0; fm < 4; fm++)
        #pragma unroll
        for (int fn = 0; fn < 4; fn++)
          #pragma unroll
          for (int r = 0; r < 4; r++)
            sE[(fm * 16 + l4 * 4 + r) * 264 + wn2 * 64 + fn * 16 + l15] = acc2[fm][fn][r];
    }
    __syncthreads();
    size_t grow = (size_t)(m0 + half * 64 + rowl);
    #pragma unroll
    for (int k = 0; k < 8; k++) {
      int c0 = cg * 4 + k * 32;
      float4 v = *(float4*)&sE[rowl * 264 + c0];
      halfx4 rv = *(const halfx4*)&y2g[grow * 256 + c0];
      float4 bb = *(const float4*)&b2[c0];
      float4 o;
      o.x = v.x + (float)rv[0] + bb.x;
      o.y = v.y + (float)rv[1] + bb.y;
      o.z = v.z + (float)rv[2] + bb.z;
      o.w = v.w + (float)rv[3] + bb.w;
      *(float4*)&outp[grow * 256 + c0] = o;
    }
    __syncthreads();
  }
}

extern "C" void kernel_launch(void* const* d_in, const int* in_sizes, int n_in,
                              void* d_out, int out_size, void* d_ws, size_t ws_size,
                              hipStream_t stream)
{
  const float* vis = (const float*)d_in[0];
  const float* tf  = (const float*)d_in[1];
  const float* n1w = (const float*)d_in[2];
  const float* n1b = (const float*)d_in[3];
  const float* qw  = (const float*)d_in[4];
  const float* qb  = (const float*)d_in[5];
  const float* kw  = (const float*)d_in[6];
  const float* kb  = (const float*)d_in[7];
  const float* vw  = (const float*)d_in[8];
  const float* vb  = (const float*)d_in[9];
  const float* ow  = (const float*)d_in[10];
  const float* ob  = (const float*)d_in[11];
  const float* gw  = (const float*)d_in[12];
  const float* gb  = (const float*)d_in[13];
  const float* ls  = (const float*)d_in[14];
  const float* al  = (const float*)d_in[15];
  const float* n2w = (const float*)d_in[16];
  const float* n2b = (const float*)d_in[17];
  const float* f1w = (const float*)d_in[18];
  const float* f1b = (const float*)d_in[19];
  const float* f2w = (const float*)d_in[20];
  const float* f2b = (const float*)d_in[21];

  char* ws = (char*)d_ws;
  const size_t MB_ = 1024ull * 1024ull;
  h16*  kS   = (h16*)(ws + 0 * MB_);      // kT: 320 KB
  h16*  vS   = (h16*)(ws + 1 * MB_);      // vT: 320 KB
  float* padf = (float*)(ws + 2 * MB_);   // [8][80] f32
  float* gate = (float*)(ws + 3 * MB_);   // 512 KB
  h16*  qwT  = (h16*)(ws + 4 * MB_);      // 128 KB
  h16*  owT  = (h16*)(ws + 5 * MB_);      // 128 KB
  h16*  f1T  = (h16*)(ws + 6 * MB_);      // 512 KB
  h16*  f2T  = (h16*)(ws + 7 * MB_);      // 512 KB
  h16*  xh   = (h16*)(ws + 16 * MB_);     // 64 MB: x
  h16*  alg  = (h16*)(ws + 144 * MB_);    // 64 MB: y2

  // merged front: text_kv (160) + conv_all (2560) + ln1 (32768) run concurrently
  prep_kernel<<<35488, 256, 0, stream>>>(
      tf, kw, kb, vw, vb, ls, kS, vS, padf,
      qw, ow, f1w, f2w, qwT, owT, f1T, f2T,
      vis, n1w, n1b, gw, gb, xh, gate);

  // fused gemmQ + attention + gemmO/LN2: q and attn-out never leave the CU
  gemmQAO_kernel<<<2048, 256, 0, stream>>>(xh, qwT, qb, kS, vS, padf,
                                           owT, ob, xh, gate, al, n2w, n2b, alg);

  // fused FFN: d_out = alg + gelu(alg@W1+b1)@W2 + b2
  ffn_fused_kernel<<<1024, 512, 0, stream>>>(alg, f1T, f1b, f2T, f2b, (float*)d_out);
}

// Round 11
// 478.322 us; speedup vs baseline: 1.0255x; 1.0255x over previous
//
#include <hip/hip_runtime.h>
#include <hip/hip_bf16.h>

typedef _Float16 h16;
typedef __attribute__((ext_vector_type(8))) _Float16 halfx8;
typedef __attribute__((ext_vector_type(4))) _Float16 halfx4;
typedef __attribute__((ext_vector_type(4))) float f32x4;

__device__ __forceinline__ void gload_lds16(const void* g, void* l) {
  __builtin_amdgcn_global_load_lds((const __attribute__((address_space(1))) unsigned int*)g,
                                   (__attribute__((address_space(3))) unsigned int*)l, 16, 0, 0);
}
__device__ __forceinline__ unsigned umax_(unsigned a, unsigned b) { return a > b ? a : b; }
__device__ __forceinline__ unsigned umin_(unsigned a, unsigned b) { return a < b ? a : b; }

// tanh-form GELU via sigmoid: x*sigmoid(1.5957691x + 0.0713548x^3)
__device__ __forceinline__ float fast_gelu(float v) {
  float x2 = v * v;
  float w_ = v * fmaf(x2, 0.0713548163f, 1.5957691216f);
  float e = __expf(w_);
  float r = 1.f / (1.f + e);
  return v * e * r;
}

// ---------------- merged prep: text_kv (blocks 0-159) + conv_all (160-2719) + ln1 (2720+) ----
__global__ __launch_bounds__(256) void prep_kernel(
    const float* __restrict__ tf, const float* __restrict__ kw, const float* __restrict__ kb,
    const float* __restrict__ vw, const float* __restrict__ vb, const float* __restrict__ lsp,
    h16* __restrict__ ko, h16* __restrict__ vo, float* __restrict__ padf,
    const float* __restrict__ qw, const float* __restrict__ ow,
    const float* __restrict__ f1w, const float* __restrict__ f2w,
    h16* __restrict__ qwT, h16* __restrict__ owT,
    h16* __restrict__ f1T, h16* __restrict__ f2T,
    const float* __restrict__ vis, const float* __restrict__ n1w, const float* __restrict__ n1b,
    const float* __restrict__ gw, const float* __restrict__ gb,
    h16* __restrict__ x, float* __restrict__ gate)
{
  __shared__ h16 st[4 * 512];
  __shared__ float kro[4 * 256];
  __shared__ float ssc[4];
  int bid = blockIdx.x, tid = threadIdx.x;
  int lane = tid & 63, wid = tid >> 6;

  if (bid < 160) {
    // ---------------- text_kv body ----------------
    int b = bid / 20, tg = bid % 20, t0 = tg * 4;
    for (int i = tid; i < 4 * 512; i += 256) {
      int tl = i >> 9, j = i & 511, t = t0 + tl;
      float v = (t < 77) ? tf[((size_t)b * 77 + t) * 512 + j] : 0.f;
      st[i] = (h16)v;
    }
    __syncthreads();
    {
      int t = t0 + wid;
      float a = 0.f;
      #pragma unroll
      for (int j = 0; j < 8; j++) a += fabsf((float)st[wid * 512 + lane + j * 64]);
      #pragma unroll
      for (int o = 32; o; o >>= 1) a += __shfl_xor(a, o);
      if (lane == 0) padf[b * 80 + t] = (a <= 1e-6f) ? -1e30f : 0.f;
    }
    int c = tid;
    float kacc[4], vacc[4];
    #pragma unroll
    for (int tl = 0; tl < 4; tl++) { kacc[tl] = kb[c]; vacc[tl] = vb[c]; }
    for (int j = 0; j < 512; j++) {
      float wkv = kw[(size_t)j * 256 + c];
      float wvv = vw[(size_t)j * 256 + c];
      #pragma unroll
      for (int tl = 0; tl < 4; tl++) {
        float xv = (float)st[tl * 512 + j];
        kacc[tl] += xv * wkv; vacc[tl] += xv * wvv;
      }
    }
    #pragma unroll
    for (int tl = 0; tl < 4; tl++) kro[tl * 256 + c] = kacc[tl] * kacc[tl];
    __syncthreads();
    {
      float s2 = kro[wid * 256 + lane] + kro[wid * 256 + lane + 64]
               + kro[wid * 256 + lane + 128] + kro[wid * 256 + lane + 192];
      #pragma unroll
      for (int o = 32; o; o >>= 1) s2 += __shfl_xor(s2, o);
      if (lane == 0) {
        float ls = lsp[0];
        float scale = __expf(fminf(fmaxf(ls, -2.f), 2.f)) * rsqrtf(32.f);
        ssc[wid] = scale / fmaxf(sqrtf(s2), 1e-6f);
      }
    }
    __syncthreads();
    int h = c >> 5, d = c & 31, g = d >> 3, e = d & 7;
    #pragma unroll
    for (int tl = 0; tl < 4; tl++) {
      int t = t0 + tl;
      int kt = t >> 4, l15 = t & 15, ln = g * 16 + l15;
      size_t koff = ((((size_t)(b * 8 + h) * 5 + kt) * 64) + ln) * 8 + e;
      size_t voff = (((size_t)(b * 8 + h) * 80) + t) * 32 + d;
      ko[koff] = (t < 77) ? (h16)(kacc[tl] * ssc[tl]) : (h16)0.f;
      vo[voff] = (t < 77) ? (h16)vacc[tl] : (h16)0.f;
    }
  } else if (bid < 2720) {
    // ---------------- conv_all body ----------------
    int cb = bid - 160;
    const float* in; h16* out; int logN, K, base;
    if (cb < 256)       { in = qw;  out = qwT; logN = 8;  K = 256;  base = 0; }
    else if (cb < 512)  { in = ow;  out = owT; logN = 8;  K = 256;  base = 256; }
    else if (cb < 1536) { in = f1w; out = f1T; logN = 10; K = 256;  base = 512; }
    else                { in = f2w; out = f2T; logN = 8;  K = 1024; base = 1536; }
    int idx = (cb - base) * 256 + tid;
    int k = idx >> logN, n = idx & ((1 << logN) - 1);
    out[(size_t)n * K + k] = (h16)in[idx];
  } else {
    // ---------------- ln1 body ----------------
    size_t row = (size_t)(bid - 2720) * 4 + wid;
    const float4 v = ((const float4*)(vis + row * 256))[lane];
    float s = v.x + v.y + v.z + v.w;
    float q = v.x * v.x + v.y * v.y + v.z * v.z + v.w * v.w;
    #pragma unroll
    for (int o = 32; o; o >>= 1) { s += __shfl_xor(s, o); q += __shfl_xor(q, o); }
    float mean = s * (1.f / 256.f);
    float rstd = rsqrtf(q * (1.f / 256.f) - mean * mean + 1e-5f);
    float4 wv = ((const float4*)n1w)[lane], bv = ((const float4*)n1b)[lane];
    float x0 = (v.x - mean) * rstd * wv.x + bv.x;
    float x1 = (v.y - mean) * rstd * wv.y + bv.y;
    float x2 = (v.z - mean) * rstd * wv.z + bv.z;
    float x3 = (v.w - mean) * rstd * wv.w + bv.w;
    float4 gv = ((const float4*)gw)[lane];
    float g = x0 * gv.x + x1 * gv.y + x2 * gv.z + x3 * gv.w;
    #pragma unroll
    for (int o = 32; o; o >>= 1) g += __shfl_xor(g, o);
    if (lane == 0) gate[row] = 1.f / (1.f + __expf(-(g + gb[0])));
    halfx4 o4; o4[0] = (h16)x0; o4[1] = (h16)x1; o4[2] = (h16)x2; o4[3] = (h16)x3;
    ((halfx4*)(x + row * 256))[lane] = o4;
  }
}

// ---------------- fused gemmQ + attention: q never leaves the CU (R5 best) ----------------
__global__ __launch_bounds__(256) void gemmQA_kernel(const h16* __restrict__ A,
    const h16* __restrict__ Wt, const float* __restrict__ bias,
    const h16* __restrict__ kk,   // kT[b][h][kt][lane][8]
    const h16* __restrict__ vv,   // vT[b][h][80][32]
    const float* __restrict__ padf,
    h16* __restrict__ outp)       // attn output (qh)
{
  __shared__ char sA[8192];
  __shared__ char sB[32768];     // K-loop B tiles; then q tile [64][256] h16 swizzled
  int m0 = blockIdx.x * 64;
  int tid = threadIdx.x, lane = tid & 63, wid = tid >> 6;
  int wn = wid;
  int l15 = lane & 15, l4 = lane >> 4, xk = l15 & 7;
  f32x4 acc[4][4];
  #pragma unroll
  for (int a = 0; a < 4; a++)
    #pragma unroll
    for (int b2 = 0; b2 < 4; b2++) acc[a][b2] = (f32x4){0.f, 0.f, 0.f, 0.f};
  const size_t sa = 512;
  int srow = lane >> 3;
  int scol = ((lane & 7) ^ srow) * 16;
  const char* Ab = (const char*)A + (size_t)m0 * sa + scol;
  const char* Bb = (const char*)Wt + scol;
  for (int k0 = 0; k0 < 256; k0 += 64) {
    #pragma unroll
    for (int cc = 0; cc < 2; cc++) {
      int ch = wid * 2 + cc;
      gload_lds16(Ab + (size_t)(ch * 8 + srow) * sa + k0 * 2, sA + ch * 1024);
    }
    #pragma unroll
    for (int cc = 0; cc < 8; cc++) {
      int ch = wid * 8 + cc;
      gload_lds16(Bb + (size_t)(ch * 8 + srow) * sa + k0 * 2, sB + ch * 1024);
    }
    asm volatile("s_waitcnt vmcnt(0)" ::: "memory");
    __syncthreads();
    #pragma unroll
    for (int ks = 0; ks < 2; ks++) {
      halfx8 af[4], bf[4];
      #pragma unroll
      for (int f = 0; f < 4; f++) {
        af[f] = *(const halfx8*)(sA + (f * 16 + l15) * 128 + (((ks * 4 + l4) ^ xk) * 16));
        bf[f] = *(const halfx8*)(sB + (wn * 64 + f * 16 + l15) * 128 + (((ks * 4 + l4) ^ xk) * 16));
      }
      #pragma unroll
      for (int fm = 0; fm < 4; fm++)
        #pragma unroll
        for (int fn = 0; fn < 4; fn++)
          acc[fm][fn] = __builtin_amdgcn_mfma_f32_16x16x32_f16(af[fm], bf[fn], acc[fm][fn], 0, 0, 0);
    }
    __syncthreads();
  }
  float bv[4];
  #pragma unroll
  for (int fn = 0; fn < 4; fn++) bv[fn] = bias[wn * 64 + fn * 16 + l15];
  float ps[4][4];
  #pragma unroll
  for (int fm = 0; fm < 4; fm++)
    #pragma unroll
    for (int r = 0; r < 4; r++) {
      float s = 0.f;
      #pragma unroll
      for (int fn = 0; fn < 4; fn++) {
        float v = acc[fm][fn][r] + bv[fn];
        acc[fm][fn][r] = v;
        s += v * v;
      }
      ps[fm][r] = s;
    }
  #pragma unroll
  for (int o = 1; o <= 8; o <<= 1)
    #pragma unroll
    for (int fm = 0; fm < 4; fm++)
      #pragma unroll
      for (int r = 0; r < 4; r++) ps[fm][r] += __shfl_xor(ps[fm][r], o);
  if (l15 == 0) {
    #pragma unroll
    for (int fm = 0; fm < 4; fm++)
      #pragma unroll
      for (int r = 0; r < 4; r++)
        ((float*)sA)[(fm * 16 + l4 * 4 + r) * 4 + wn] = ps[fm][r];
  }
  __syncthreads();
  // normalized q -> sB as [64 rows][256 cols] h16, granule ^ (row&7) swizzle
  #pragma unroll
  for (int fm = 0; fm < 4; fm++)
    #pragma unroll
    for (int r = 0; r < 4; r++) {
      const float* p = (const float*)sA + (fm * 16 + l4 * 4 + r) * 4;
      float S = p[0] + p[1] + p[2] + p[3];
      float sc = 1.f / fmaxf(sqrtf(S), 1e-6f);
      int row = fm * 16 + l4 * 4 + r;
      #pragma unroll
      for (int fn = 0; fn < 4; fn++) {
        int col = wn * 64 + fn * 16 + l15;
        ((h16*)(sB + row * 512 + (((col >> 3) ^ (row & 7)) * 16)))[col & 7] =
            (h16)(acc[fm][fn][r] * sc);
      }
    }
  __syncthreads();

  // ---- attn phase: wave = rows wid*16..+16; qf frags from LDS ----
  {
    int bx = blockIdx.x;
    int g = l4;
    int b = bx >> 8;
    size_t qrow = (size_t)bx * 64 + wid * 16 + l15;
    int base4 = g * 4;
    float pad4[5][4];
    #pragma unroll
    for (int kt = 0; kt < 5; kt++) {
      float4 p4 = *(const float4*)&padf[b * 80 + kt * 16 + base4];
      pad4[kt][0] = p4.x; pad4[kt][1] = p4.y; pad4[kt][2] = p4.z; pad4[kt][3] = p4.w;
    }
    const char* qsrc = sB + (wid * 16 + l15) * 512;
    int rk = l15 & 7;  // row&7 for swizzle key
    h16* op = &outp[qrow * 256 + g * 8];
    #pragma unroll 2
    for (int h = 0; h < 8; h++) {
      int ho = h * 32;
      halfx8 qf = *(const halfx8*)(qsrc + (((h * 4 + l4) ^ rk) * 16));
      const h16* kph = kk + (((size_t)(b * 8 + h) * 5) * 64 + lane) * 8;
      const h16* vph = vv + ((size_t)(b * 8 + h) * 80) * 32 + g * 8;
      f32x4 acc5[5];
      #pragma unroll
      for (int kt = 0; kt < 5; kt++) {
        halfx8 kf = *(const halfx8*)(kph + kt * 512);
        acc5[kt] = __builtin_amdgcn_mfma_f32_16x16x32_f16(kf, qf, (f32x4){0.f, 0.f, 0.f, 0.f}, 0, 0, 0);
      }
      unsigned pv0 = 0u, pv1 = 0u, pv2 = 0u, pv3 = 0u, pv4 = 0u;
      #pragma unroll
      for (int kt = 0; kt < 5; kt++) {
        #pragma unroll
        for (int r = 0; r < 4; r++) {
          float s = acc5[kt][r] + pad4[kt][r];
          int bi = __float_as_int(s);
          unsigned u = ((unsigned)(bi ^ ((bi >> 31) | (int)0x80000000)) & 0xFFFFFF80u)
                     | (unsigned)(base4 + kt * 16 + r);
          unsigned a;
          a = umax_(pv0, u); u = umin_(pv0, u); pv0 = a;
          a = umax_(pv1, u); u = umin_(pv1, u); pv1 = a;
          a = umax_(pv2, u); u = umin_(pv2, u); pv2 = a;
          a = umax_(pv3, u); u = umin_(pv3, u); pv3 = a;
          pv4 = umax_(pv4, u);
        }
      }
      #pragma unroll
      for (int mrd = 0; mrd < 2; mrd++) {
        int msk = mrd ? 32 : 16;
        unsigned b0 = (unsigned)__shfl_xor((int)pv0, msk);
        unsigned b1 = (unsigned)__shfl_xor((int)pv1, msk);
        unsigned b2 = (unsigned)__shfl_xor((int)pv2, msk);
        unsigned b3 = (unsigned)__shfl_xor((int)pv3, msk);
        unsigned b4 = (unsigned)__shfl_xor((int)pv4, msk);
        unsigned c0 = umax_(pv0, b0);
        unsigned c1 = umax_(umax_(umin_(pv0, b0), pv1), b1);
        unsigned c2 = umax_(umax_(umin_(pv0, b1), umin_(pv1, b0)), umax_(pv2, b2));
        unsigned c3 = umax_(umax_(umax_(umin_(pv0, b2), umin_(pv1, b1)), umin_(pv2, b0)), umax_(pv3, b3));
        unsigned c4 = umax_(umax_(umax_(umin_(pv0, b3), umin_(pv1, b2)),
                                  umax_(umin_(pv2, b1), umin_(pv3, b0))), umax_(pv4, b4));
        pv0 = c0; pv1 = c1; pv2 = c2; pv3 = c3; pv4 = c4;
      }
      unsigned pvs[5] = {pv0, pv1, pv2, pv3, pv4};
      float pw[5]; int ti[5]; float den = 0.f;
      #pragma unroll
      for (int k = 0; k < 5; k++) {
        unsigned u = pvs[k];
        int sg = ((int)u) >> 31;
        float tv = __int_as_float(u ^ (0x80000000u | (unsigned)~sg));
        ti[k] = (int)(u & 0x7Fu);
        pw[k] = __expf(tv);
        den += pw[k];
      }
      float inv = 1.f / den;
      halfx8 o8 = {};
      #pragma unroll
      for (int k = 0; k < 5; k++) {
        h16 ph = (h16)(pw[k] * inv);
        halfx8 v = *(const halfx8*)(vph + ti[k] * 32);
        halfx8 p8 = {ph, ph, ph, ph, ph, ph, ph, ph};
        o8 = o8 + p8 * v;
      }
      *(halfx8*)(op + ho) = o8;
    }
  }
}

// ---------------- gemmO: y2 = LN2(x + alpha*gate*(aligned @ owT^T + ob)), T2-swizzled ----------------
__global__ __launch_bounds__(256) void gemmO_kernel(const h16* __restrict__ A,
    const h16* __restrict__ Wt, const float* __restrict__ ob,
    const h16* __restrict__ x, const float* __restrict__ gate,
    const float* __restrict__ alphap, const float* __restrict__ w2,
    const float* __restrict__ b2, h16* __restrict__ outp)
{
  __shared__ char sA[8192];
  __shared__ char sB[32768];
  int m0 = blockIdx.x * 64;
  int tid = threadIdx.x, lane = tid & 63, wid = tid >> 6;
  int wn = wid;
  int l15 = lane & 15, l4 = lane >> 4, xk = l15 & 7;
  f32x4 acc[4][4];
  #pragma unroll
  for (int a = 0; a < 4; a++)
    #pragma unroll
    for (int b2_ = 0; b2_ < 4; b2_++) acc[a][b2_] = (f32x4){0.f, 0.f, 0.f, 0.f};
  const size_t sa = 512;
  int srow = lane >> 3;
  int scol = ((lane & 7) ^ srow) * 16;
  const char* Ab = (const char*)A + (size_t)m0 * sa + scol;
  const char* Bb = (const char*)Wt + scol;
  for (int k0 = 0; k0 < 256; k0 += 64) {
    #pragma unroll
    for (int cc = 0; cc < 2; cc++) {
      int ch = wid * 2 + cc;
      gload_lds16(Ab + (size_t)(ch * 8 + srow) * sa + k0 * 2, sA + ch * 1024);
    }
    #pragma unroll
    for (int cc = 0; cc < 8; cc++) {
      int ch = wid * 8 + cc;
      gload_lds16(Bb + (size_t)(ch * 8 + srow) * sa + k0 * 2, sB + ch * 1024);
    }
    asm volatile("s_waitcnt vmcnt(0)" ::: "memory");
    __syncthreads();
    #pragma unroll
    for (int ks = 0; ks < 2; ks++) {
      halfx8 af[4], bf[4];
      #pragma unroll
      for (int f = 0; f < 4; f++) {
        af[f] = *(const halfx8*)(sA + (f * 16 + l15) * 128 + (((ks * 4 + l4) ^ xk) * 16));
        bf[f] = *(const halfx8*)(sB + (wn * 64 + f * 16 + l15) * 128 + (((ks * 4 + l4) ^ xk) * 16));
      }
      #pragma unroll
      for (int fm = 0; fm < 4; fm++)
        #pragma unroll
        for (int fn = 0; fn < 4; fn++)
          acc[fm][fn] = __builtin_amdgcn_mfma_f32_16x16x32_f16(af[fm], bf[fn], acc[fm][fn], 0, 0, 0);
    }
    __syncthreads();
  }
  float bv[4], w2v[4], b2v[4];
  #pragma unroll
  for (int fn = 0; fn < 4; fn++) {
    int col = wn * 64 + fn * 16 + l15;
    bv[fn] = ob[col]; w2v[fn] = w2[col]; b2v[fn] = b2[col];
  }
  float al = alphap[0];
  float s1[4][4], s2[4][4];
  #pragma unroll
  for (int fm = 0; fm < 4; fm++)
    #pragma unroll
    for (int r = 0; r < 4; r++) {
      size_t row = (size_t)(m0 + fm * 16 + l4 * 4 + r);
      float ga = al * gate[row];
      float a1 = 0.f, a2 = 0.f;
      #pragma unroll
      for (int fn = 0; fn < 4; fn++) {
        float v = acc[fm][fn][r] + bv[fn];
        float xv = (float)x[row * 256 + wn * 64 + fn * 16 + l15];
        float y = xv + ga * v;
        acc[fm][fn][r] = y;
        a1 += y; a2 += y * y;
      }
      s1[fm][r] = a1; s2[fm][r] = a2;
    }
  #pragma unroll
  for (int o = 1; o <= 8; o <<= 1)
    #pragma unroll
    for (int fm = 0; fm < 4; fm++)
      #pragma unroll
      for (int r = 0; r < 4; r++) {
        s1[fm][r] += __shfl_xor(s1[fm][r], o);
        s2[fm][r] += __shfl_xor(s2[fm][r], o);
      }
  if (l15 == 0) {
    #pragma unroll
    for (int fm = 0; fm < 4; fm++)
      #pragma unroll
      for (int r = 0; r < 4; r++) {
        int rr = fm * 16 + l4 * 4 + r;
        ((float*)sA)[rr * 8 + wn * 2 + 0] = s1[fm][r];
        ((float*)sA)[rr * 8 + wn * 2 + 1] = s2[fm][r];
      }
  }
  __syncthreads();
  #pragma unroll
  for (int fm = 0; fm < 4; fm++)
    #pragma unroll
    for (int r = 0; r < 4; r++) {
      int rr = fm * 16 + l4 * 4 + r;
      const float* p = (const float*)sA + rr * 8;
      float S1 = p[0] + p[2] + p[4] + p[6];
      float S2 = p[1] + p[3] + p[5] + p[7];
      float mean = S1 * (1.f / 256.f);
      float var = S2 * (1.f / 256.f) - mean * mean;
      float rstd = rsqrtf(var + 1e-5f);
      size_t row = (size_t)(m0 + rr);
      #pragma unroll
      for (int fn = 0; fn < 4; fn++) {
        float y = acc[fm][fn][r];
        outp[row * 256 + wn * 64 + fn * 16 + l15] =
            (h16)((y - mean) * rstd * w2v[fn] + b2v[fn]);
      }
    }
}

// ---------------- fused FFN v7: v4 pipeline + swapped gemm1 -> H^T regs -> b64 H stores ----
// gemm1 computes H^T = mfma(W1frag, y2frag) (bit-identical products): thread then holds 4
// n1-CONTIGUOUS values -> gelu+pack -> ONE ds_write_b64 per frag (16 b16 -> 4 b64 stores).
// sH slot swizzle: slot ^ ((row&7)<<1) — pair-preserving (b128 reads stay contiguous).
__device__ __forceinline__ void ffn_stage_w1(const h16* __restrict__ w1t,
                                             int c, char* dW1, int tid, int wid)
{
  #pragma unroll
  for (int j = 0; j < 4; j++) {
    int i = j * 512 + tid;
    int r = i >> 5, g = i & 31;
    gload_lds16(w1t + (size_t)(c * 64 + r) * 256 + ((g ^ (r & 7)) * 8),
                dW1 + (j * 512 + wid * 64) * 16);
  }
}
__device__ __forceinline__ void ffn_stage_w2(const h16* __restrict__ w2t,
                                             int c, char* dW2, int tid, int wid)
{
  #pragma unroll
  for (int j = 0; j < 4; j++) {
    int i = j * 512 + tid;
    int r = i >> 3, g = i & 7;
    gload_lds16(w2t + (size_t)r * 1024 + c * 64 + ((g ^ (r & 7)) * 8),
                dW2 + (j * 512 + wid * 64) * 16);
  }
}

__global__ __launch_bounds__(512, 2) void ffn_fused_kernel(
    const h16* __restrict__ y2g, const h16* __restrict__ w1t, const float* __restrict__ b1,
    const h16* __restrict__ w2t, const float* __restrict__ b2, float* __restrict__ outp)
{
  __shared__ char smem[163840];
  float* sE = (float*)smem;

  int m0 = blockIdx.x * 128;
  int tid = threadIdx.x, lane = tid & 63, wid = tid >> 6;
  int l15 = lane & 15, l4 = lane >> 4;
  int wm1 = wid >> 1, wn1 = wid & 1;
  int wm2 = wid >> 2, wn2 = wid & 3;

  halfx8 afy[2][8];
  #pragma unroll
  for (int fm = 0; fm < 2; fm++) {
    size_t row = (size_t)(m0 + wm1 * 32 + fm * 16 + l15);
    #pragma unroll
    for (int ks = 0; ks < 8; ks++)
      afy[fm][ks] = *(const halfx8*)&y2g[row * 256 + ks * 32 + l4 * 8];
  }

  f32x4 acc2[4][4];
  #pragma unroll
  for (int a = 0; a < 4; a++)
    #pragma unroll
    for (int b_ = 0; b_ < 4; b_++) acc2[a][b_] = (f32x4){0.f, 0.f, 0.f, 0.f};

  ffn_stage_w1(w1t, 0, smem, tid, wid);
  // b1 as float4 (index depends on l4*4+r after the operand swap)
  float4 b1v[2];
  b1v[0] = *(const float4*)&b1[wn1 * 32 + l4 * 4];
  b1v[1] = *(const float4*)&b1[wn1 * 32 + 16 + l4 * 4];
  asm volatile("s_waitcnt vmcnt(0)" ::: "memory");
  __builtin_amdgcn_s_barrier();
  asm volatile("" ::: "memory");

  for (int c = 0; c < 16; c++) {
    int buf = c & 1;
    char* sW1c = smem + buf * 32768;
    if (c < 15) ffn_stage_w1(w1t, c + 1, smem + (buf ^ 1) * 32768, tid, wid);
    ffn_stage_w2(w2t, c, smem + 65536 + buf * 32768, tid, wid);
    float4 nb0 = {0.f, 0.f, 0.f, 0.f}, nb1 = {0.f, 0.f, 0.f, 0.f};
    if (c < 15) {
      nb0 = *(const float4*)&b1[(c + 1) * 64 + wn1 * 32 + l4 * 4];
      nb1 = *(const float4*)&b1[(c + 1) * 64 + wn1 * 32 + 16 + l4 * 4];
    }

    // gemm1(c): H^T = mfma(W1frag, y2frag) — swapped operands
    f32x4 a1[2][2];
    #pragma unroll
    for (int a = 0; a < 2; a++)
      #pragma unroll
      for (int b_ = 0; b_ < 2; b_++) a1[a][b_] = (f32x4){0.f, 0.f, 0.f, 0.f};
    __builtin_amdgcn_s_setprio(1);
    #pragma unroll
    for (int ks = 0; ks < 8; ks++) {
      #pragma unroll
      for (int fc = 0; fc < 2; fc++) {
        int nrow = wn1 * 32 + fc * 16 + l15;
        halfx8 bf = *(const halfx8*)(sW1c + (size_t)nrow * 512 + (((ks * 4 + l4) ^ (nrow & 7)) * 16));
        #pragma unroll
        for (int fm = 0; fm < 2; fm++)
          a1[fm][fc] = __builtin_amdgcn_mfma_f32_16x16x32_f16(bf, afy[fm][ks], a1[fm][fc], 0, 0, 0);
      }
    }
    __builtin_amdgcn_s_setprio(0);

    // gelu(c) -> sH[buf]: packed b64 stores, slot swizzle ^((row&7)<<1)
    {
      char* sHc = smem + 131072 + buf * 16384;
      #pragma unroll
      for (int fm = 0; fm < 2; fm++) {
        int row = wm1 * 32 + fm * 16 + l15;
        int sx = (row & 7) << 1;
        #pragma unroll
        for (int fc = 0; fc < 2; fc++) {
          int slot = wn1 * 8 + fc * 4 + l4;
          float4 bb = b1v[fc];
          halfx4 hv;
          hv[0] = (h16)fast_gelu(a1[fm][fc][0] + bb.x);
          hv[1] = (h16)fast_gelu(a1[fm][fc][1] + bb.y);
          hv[2] = (h16)fast_gelu(a1[fm][fc][2] + bb.z);
          hv[3] = (h16)fast_gelu(a1[fm][fc][3] + bb.w);
          *(halfx4*)(sHc + row * 128 + ((slot ^ sx) * 8)) = hv;
        }
      }
    }

    // gemm2(c-1): ah from sH[buf^1], bw from sW2[buf^1]
    if (c > 0) {
      char* sHp = smem + 131072 + (buf ^ 1) * 16384;
      char* sW2p = smem + 65536 + (buf ^ 1) * 32768;
      __builtin_amdgcn_s_setprio(1);
      #pragma unroll
      for (int ks = 0; ks < 2; ks++) {
        halfx8 ah[4], bw[4];
        #pragma unroll
        for (int f = 0; f < 4; f++) {
          int hrow = wm2 * 64 + f * 16 + l15;
          ah[f] = *(const halfx8*)(sHp + hrow * 128 + (((ks * 8 + l4 * 2) ^ ((hrow & 7) << 1)) * 8));
          int wrow = wn2 * 64 + f * 16 + l15;
          bw[f] = *(const halfx8*)(sW2p + (size_t)wrow * 128 + (((ks * 4 + l4) ^ (wrow & 7)) * 16));
        }
        #pragma unroll
        for (int fm = 0; fm < 4; fm++)
          #pragma unroll
          for (int fn = 0; fn < 4; fn++)
            acc2[fm][fn] = __builtin_amdgcn_mfma_f32_16x16x32_f16(ah[fm], bw[fn], acc2[fm][fn], 0, 0, 0);
      }
      __builtin_amdgcn_s_setprio(0);
    }

    asm volatile("s_waitcnt lgkmcnt(0)" ::: "memory");
    asm volatile("s_waitcnt vmcnt(0)" ::: "memory");
    __builtin_amdgcn_s_barrier();
    asm volatile("" ::: "memory");
    b1v[0] = nb0; b1v[1] = nb1;
  }

  // final gemm2(15)
  {
    char* sHp = smem + 131072 + 16384;
    char* sW2p = smem + 65536 + 32768;
    __builtin_amdgcn_s_setprio(1);
    #pragma unroll
    for (int ks = 0; ks < 2; ks++) {
      halfx8 ah[4], bw[4];
      #pragma unroll
      for (int f = 0; f < 4; f++) {
        int hrow = wm2 * 64 + f * 16 + l15;
        ah[f] = *(const halfx8*)(sHp + hrow * 128 + (((ks * 8 + l4 * 2) ^ ((hrow & 7) << 1)) * 8));
        int wrow = wn2 * 64 + f * 16 + l15;
        bw[f] = *(const halfx8*)(sW2p + (size_t)wrow * 128 + (((ks * 4 + l4) ^ (wrow & 7)) * 16));
      }
      #pragma unroll
      for (int fm = 0; fm < 4; fm++)
        #pragma unroll
        for (int fn = 0; fn < 4; fn++)
          acc2[fm][fn] = __builtin_amdgcn_mfma_f32_16x16x32_f16(ah[fm], bw[fn], acc2[fm][fn], 0, 0, 0);
    }
    __builtin_amdgcn_s_setprio(0);
  }

  int rowl = tid >> 3, cg = tid & 7;
  #pragma unroll
  for (int half = 0; half < 2; half++) {
    if (wm2 == half) {
      #pragma unroll
      for (int fm = 0; fm < 4; fm++)
        #pragma unroll
        for (int fn = 0; fn < 4; fn++)
          #pragma unroll
          for (int r = 0; r < 4; r++)
            sE[(fm * 16 + l4 * 4 + r) * 264 + wn2 * 64 + fn * 16 + l15] = acc2[fm][fn][r];
    }
    __syncthreads();
    size_t grow = (size_t)(m0 + half * 64 + rowl);
    #pragma unroll
    for (int k = 0; k < 8; k++) {
      int c0 = cg * 4 + k * 32;
      float4 v = *(float4*)&sE[rowl * 264 + c0];
      halfx4 rv = *(const halfx4*)&y2g[grow * 256 + c0];
      float4 bb = *(const float4*)&b2[c0];
      float4 o;
      o.x = v.x + (float)rv[0] + bb.x;
      o.y = v.y + (float)rv[1] + bb.y;
      o.z = v.z + (float)rv[2] + bb.z;
      o.w = v.w + (float)rv[3] + bb.w;
      *(float4*)&outp[grow * 256 + c0] = o;
    }
    __syncthreads();
  }
}

extern "C" void kernel_launch(void* const* d_in, const int* in_sizes, int n_in,
                              void* d_out, int out_size, void* d_ws, size_t ws_size,
                              hipStream_t stream)
{
  const float* vis = (const float*)d_in[0];
  const float* tf  = (const float*)d_in[1];
  const float* n1w = (const float*)d_in[2];
  const float* n1b = (const float*)d_in[3];
  const float* qw  = (const float*)d_in[4];
  const float* qb  = (const float*)d_in[5];
  const float* kw  = (const float*)d_in[6];
  const float* kb  = (const float*)d_in[7];
  const float* vw  = (const float*)d_in[8];
  const float* vb  = (const float*)d_in[9];
  const float* ow  = (const float*)d_in[10];
  const float* ob  = (const float*)d_in[11];
  const float* gw  = (const float*)d_in[12];
  const float* gb  = (const float*)d_in[13];
  const float* ls  = (const float*)d_in[14];
  const float* al  = (const float*)d_in[15];
  const float* n2w = (const float*)d_in[16];
  const float* n2b = (const float*)d_in[17];
  const float* f1w = (const float*)d_in[18];
  const float* f1b = (const float*)d_in[19];
  const float* f2w = (const float*)d_in[20];
  const float* f2b = (const float*)d_in[21];

  char* ws = (char*)d_ws;
  const size_t MB_ = 1024ull * 1024ull;
  h16*  kS   = (h16*)(ws + 0 * MB_);      // kT: 320 KB
  h16*  vS   = (h16*)(ws + 1 * MB_);      // vT: 320 KB
  float* padf = (float*)(ws + 2 * MB_);   // [8][80] f32
  float* gate = (float*)(ws + 3 * MB_);   // 512 KB
  h16*  qwT  = (h16*)(ws + 4 * MB_);      // 128 KB
  h16*  owT  = (h16*)(ws + 5 * MB_);      // 128 KB
  h16*  f1T  = (h16*)(ws + 6 * MB_);      // 512 KB
  h16*  f2T  = (h16*)(ws + 7 * MB_);      // 512 KB
  h16*  xh   = (h16*)(ws + 16 * MB_);     // 64 MB: x
  h16*  qh   = (h16*)(ws + 80 * MB_);     // 64 MB: attn out
  h16*  alg  = (h16*)(ws + 144 * MB_);    // 64 MB: y2

  // merged front: text_kv (160) + conv_all (2560) + ln1 (32768) run concurrently
  prep_kernel<<<35488, 256, 0, stream>>>(
      tf, kw, kb, vw, vb, ls, kS, vS, padf,
      qw, ow, f1w, f2w, qwT, owT, f1T, f2T,
      vis, n1w, n1b, gw, gb, xh, gate);

  // fused gemmQ + attention: q stays in LDS; writes attn-out directly
  gemmQA_kernel<<<2048, 256, 0, stream>>>(xh, qwT, qb, kS, vS, padf, qh);

  gemmO_kernel<<<2048, 256, 0, stream>>>(qh, owT, ob, xh, gate, al, n2w, n2b, alg);

  // fused FFN: d_out = alg + gelu(alg@W1+b1)@W2 + b2
  ffn_fused_kernel<<<1024, 512, 0, stream>>>(alg, f1T, f1b, f2T, f2b, (float*)d_out);
}